// Round 4
// baseline (1070.682 us; speedup 1.0000x reference)
//
#include <hip/hip_runtime.h>

#define NEPS 1e-5f

__device__ inline unsigned int bfpack(float a, float b) {
  unsigned int ua = __float_as_uint(a), ub = __float_as_uint(b);
  ua += 0x7fff + ((ua >> 16) & 1);
  ub += 0x7fff + ((ub >> 16) & 1);
  return (ua >> 16) | (ub & 0xffff0000u);
}
__device__ inline float bflo(unsigned int u) { return __uint_as_float(u << 16); }
__device__ inline float bfhi(unsigned int u) { return __uint_as_float(u & 0xffff0000u); }

// ---------------- CSR build (+ fused x-stats) ----------------
__global__ void k_degx(const int* __restrict__ ei, int* __restrict__ deg_cnt,
                       int* __restrict__ slot, const float* __restrict__ x,
                       float* __restrict__ stats, int N_, int E_) {
  int i = blockIdx.x * blockDim.x + threadIdx.x;
  int stride = gridDim.x * blockDim.x;
  for (int e = i; e < E_; e += stride) slot[e] = atomicAdd(&deg_cnt[ei[E_ + e]], 1);
  // BN0 stats on x (3 channels)
  float s1[3] = {0, 0, 0}, s2[3] = {0, 0, 0};
  for (int n = i; n < N_; n += stride) {
    #pragma unroll
    for (int c = 0; c < 3; c++) { float v = x[n * 3 + c]; s1[c] += v; s2[c] += v * v; }
  }
  #pragma unroll
  for (int c = 0; c < 3; c++) {
    for (int off = 32; off > 0; off >>= 1) {
      s1[c] += __shfl_down(s1[c], off);
      s2[c] += __shfl_down(s2[c], off);
    }
  }
  if ((threadIdx.x & 63) == 0 && s1[0] == s1[0]) {
    #pragma unroll
    for (int c = 0; c < 3; c++) { atomicAdd(&stats[c], s1[c]); atomicAdd(&stats[4 + c], s2[c]); }
  }
}

__global__ __launch_bounds__(256) void k_scanA(const int* __restrict__ cnt, int* __restrict__ rp1,
                                               int* __restrict__ bsum, int N_) {
  int b = blockIdx.x, t = threadIdx.x;
  int i = b * 256 + t;
  int lane = t & 63, w = t >> 6;
  int sv = (i < N_) ? cnt[i] : 0;
  #pragma unroll
  for (int off = 1; off < 64; off <<= 1) {
    int u = __shfl_up(sv, off);
    if (lane >= off) sv += u;
  }
  __shared__ int wsum[4];
  if (lane == 63) wsum[w] = sv;
  __syncthreads();
  int add = 0;
  for (int k = 0; k < w; k++) add += wsum[k];
  sv += add;
  if (i < N_) rp1[i] = sv;
  if (t == 255) bsum[b] = sv;
}

__global__ __launch_bounds__(256) void k_scanB(int* __restrict__ bsum, int NB) {
  int t = threadIdx.x;
  int lane = t & 63, w = t >> 6;
  int sv = (t < NB) ? bsum[t] : 0;
  #pragma unroll
  for (int off = 1; off < 64; off <<= 1) {
    int u = __shfl_up(sv, off);
    if (lane >= off) sv += u;
  }
  __shared__ int wsum[4];
  if (lane == 63) wsum[w] = sv;
  __syncthreads();
  int add = 0;
  for (int k = 0; k < w; k++) add += wsum[k];
  sv += add;
  if (t < NB) bsum[t] = sv;
}

// add block offsets; compute dis; pack xp = {x0,x1,x2,dis}
__global__ __launch_bounds__(256) void k_scanC(int* __restrict__ row_ptr, const int* __restrict__ bsum,
                                               const int* __restrict__ deg_cnt, const float* __restrict__ x,
                                               float* __restrict__ dis, float4* __restrict__ xp, int N_) {
  int b = blockIdx.x;
  int i = b * 256 + threadIdx.x;
  if (i == 0) row_ptr[0] = 0;
  if (i >= N_) return;
  int base = b ? bsum[b - 1] : 0;
  row_ptr[i + 1] += base;
  float dg = (float)deg_cnt[i] + 1.0f;
  float ds_ = rsqrtf(dg);
  dis[i] = ds_;
  float4 v;
  v.x = x[i * 3 + 0]; v.y = x[i * 3 + 1]; v.z = x[i * 3 + 2]; v.w = ds_;
  xp[i] = v;
}

// atomic-free scatter using precomputed slots
__global__ void k_scatter(const int* __restrict__ ei, const int* __restrict__ row_ptr,
                          const int* __restrict__ slot, int* __restrict__ csr, int E_) {
  int i = blockIdx.x * blockDim.x + threadIdx.x;
  int stride = gridDim.x * blockDim.x;
  for (int e = i; e < E_; e += stride) {
    csr[row_ptr[ei[E_ + e]] + slot[e]] = ei[e];
  }
}

// fold BN0 into W1
__global__ void k_prep0(const float* __restrict__ stats, const float* __restrict__ g0,
                        const float* __restrict__ b0, const float* __restrict__ W1,
                        float* __restrict__ W1a, float* __restrict__ u1, int N_) {
  __shared__ float a[3], dd[3];
  int t = threadIdx.x;
  if (t < 3) {
    float m = stats[t] / N_;
    float v = stats[4 + t] / N_ - m * m;
    float sc = g0[t] * rsqrtf(v + NEPS);
    a[t] = sc; dd[t] = b0[t] - m * sc;
  }
  __syncthreads();
  if (t < 128) {
    float u = 0.f;
    #pragma unroll
    for (int c = 0; c < 3; c++) {
      float w = W1[c * 128 + t];
      W1a[c * 128 + t] = a[c] * w;
      u = fmaf(dd[c], w, u);
    }
    u1[t] = u;
  }
}

// ---------------- fused layer 1: gather(x) + GEMM(3->128) + relu + stats ----------------
__global__ __launch_bounds__(256) void k_layer1(const float4* __restrict__ xp,
                                                const int* __restrict__ csr,
                                                const int* __restrict__ row_ptr,
                                                const float* __restrict__ W1a,
                                                const float* __restrict__ u1,
                                                const float* __restrict__ b1,
                                                float* __restrict__ y,
                                                float* __restrict__ S1, float* __restrict__ S2,
                                                int N_) {
  __shared__ float wl[5 * 128];
  int t = threadIdx.x;
  for (int i = t; i < 384; i += 256) wl[i] = W1a[i];
  for (int i = t; i < 128; i += 256) { wl[384 + i] = u1[i]; wl[512 + i] = b1[i]; }
  __syncthreads();
  int lane = t & 63, w = t >> 6;
  int c0 = lane * 2;
  float2 w0 = *(const float2*)&wl[c0];
  float2 w1 = *(const float2*)&wl[128 + c0];
  float2 w2 = *(const float2*)&wl[256 + c0];
  float2 uu = *(const float2*)&wl[384 + c0];
  float2 bb = *(const float2*)&wl[512 + c0];
  int wid = blockIdx.x * 4 + w;
  int nw = gridDim.x * 4;
  float s1x = 0, s1y = 0, s2x = 0, s2y = 0;
  for (int n = wid; n < N_; n += nw) {
    int st = row_ptr[n], en = row_ptr[n + 1];
    float a0 = 0, a1 = 0, a2 = 0, sd = 0;
    for (int chunk = st; chunk < en; chunk += 64) {
      int cnt = min(64, en - chunk);
      if (lane < cnt) {
        float4 v = xp[csr[chunk + lane]];
        a0 = fmaf(v.w, v.x, a0);
        a1 = fmaf(v.w, v.y, a1);
        a2 = fmaf(v.w, v.z, a2);
        sd += v.w;
      }
    }
    #pragma unroll
    for (int m = 1; m < 64; m <<= 1) {
      a0 += __shfl_xor(a0, m);
      a1 += __shfl_xor(a1, m);
      a2 += __shfl_xor(a2, m);
      sd += __shfl_xor(sd, m);
    }
    float4 xn = xp[n];
    float dn = xn.w;
    a0 = fmaf(dn, xn.x, a0);
    a1 = fmaf(dn, xn.y, a1);
    a2 = fmaf(dn, xn.z, a2);
    sd += dn;
    float z0 = dn * a0, z1 = dn * a1, z2 = dn * a2, zw = dn * sd;
    float ox = fmaxf(fmaf(z0, w0.x, fmaf(z1, w1.x, fmaf(z2, w2.x, fmaf(zw, uu.x, bb.x)))), 0.f);
    float oy = fmaxf(fmaf(z0, w0.y, fmaf(z1, w1.y, fmaf(z2, w2.y, fmaf(zw, uu.y, bb.y)))), 0.f);
    s1x += ox; s1y += oy; s2x += ox * ox; s2y += oy * oy;
    float2 o; o.x = ox; o.y = oy;
    *(float2*)&y[(size_t)n * 128 + c0] = o;
  }
  __shared__ float rs[4][64][4];
  rs[w][lane][0] = s1x; rs[w][lane][1] = s1y;
  rs[w][lane][2] = s2x; rs[w][lane][3] = s2y;
  __syncthreads();
  int s = t >> 7, c = t & 127;
  int lsrc = c >> 1, sl = (s << 1) | (c & 1);
  float a = rs[0][lsrc][sl] + rs[1][lsrc][sl] + rs[2][lsrc][sl] + rs[3][lsrc][sl];
  atomicAdd(s ? &S2[c] : &S1[c], a);
}

// fold BN(prev) into W  (16 blocks)
__global__ __launch_bounds__(256) void k_prepW(const float* __restrict__ S1, const float* __restrict__ S2,
                                               const float* __restrict__ g_, const float* __restrict__ b_,
                                               const float* __restrict__ W, float* __restrict__ Wp,
                                               float* __restrict__ cb, int N_) {
  __shared__ float sc[128], sh[128];
  int t = threadIdx.x, b = blockIdx.x;
  if (t < 128) {
    float m = S1[t] / N_;
    float v = S2[t] / N_ - m * m;
    float s = g_[t] * rsqrtf(v + NEPS);
    sc[t] = s; sh[t] = b_[t] - m * s;
  }
  __syncthreads();
  for (int idx = b * 1024 + t; idx < (b + 1) * 1024; idx += 256) Wp[idx] = sc[idx >> 7] * W[idx];
  if (t < 8) {
    int j = b * 8 + t;
    float acc = 0;
    for (int k = 0; k < 128; k++) acc = fmaf(sh[k], W[k * 128 + j], acc);
    cb[j] = acc;
  }
}

// hwp = dis[n] * (y @ Wp + cb)  -> bf16 (premultiplied by own norm); row N_ zeroed (sentinel)
__global__ __launch_bounds__(256) void k_gemm(const float* __restrict__ y,
                                              const float* __restrict__ Wp,
                                              const float* __restrict__ cb,
                                              const float* __restrict__ dis,
                                              unsigned short* __restrict__ hwb, int N_) {
  int t = threadIdx.x;
  if (blockIdx.x == 0 && t < 64) ((unsigned int*)&hwb[(size_t)N_ * 128])[t] = 0;
  __shared__ float yl[64][128];
  int base = blockIdx.x * 64;
  for (int i = t; i < 64 * 32; i += 256) {
    int r = i >> 5;
    int cq = (i & 31) * 4;
    int n = base + r;
    float4 v = (n < N_) ? *(const float4*)&y[(size_t)n * 128 + cq] : float4{0, 0, 0, 0};
    *(float4*)&yl[r][cq] = v;
  }
  __syncthreads();
  int tn = t >> 5, tj = t & 31;
  float4 acc[8];
  float4 cbv = *(const float4*)&cb[tj * 4];
  #pragma unroll
  for (int r = 0; r < 8; r++) acc[r] = cbv;
  for (int kk = 0; kk < 128; kk++) {
    float4 wv = *(const float4*)&Wp[kk * 128 + tj * 4];
    #pragma unroll
    for (int r = 0; r < 8; r++) {
      float yv = yl[tn * 8 + r][kk];
      acc[r].x = fmaf(yv, wv.x, acc[r].x);
      acc[r].y = fmaf(yv, wv.y, acc[r].y);
      acc[r].z = fmaf(yv, wv.z, acc[r].z);
      acc[r].w = fmaf(yv, wv.w, acc[r].w);
    }
  }
  #pragma unroll
  for (int r = 0; r < 8; r++) {
    int n = base + tn * 8 + r;
    if (n < N_) {
      float dn = dis[n];
      uint2 o;
      o.x = bfpack(acc[r].x * dn, acc[r].y * dn);
      o.y = bfpack(acc[r].z * dn, acc[r].w * dn);
      *(uint2*)&hwb[(size_t)n * 128 + tj * 4] = o;
    }
  }
}

// gather of premultiplied bf16 rows: plain row-sum, 4 rows per wave-iteration,
// sentinel row N_ for tail lanes; fused stats; optional fused pool.
template <int FUSE_POOL>
__global__ __launch_bounds__(256) void k_gatherb(const unsigned short* __restrict__ hwb,
                                                 const int* __restrict__ csr,
                                                 const int* __restrict__ row_ptr,
                                                 const float* __restrict__ dis,
                                                 const float* __restrict__ bL,
                                                 float* __restrict__ y,
                                                 float* __restrict__ S1, float* __restrict__ S2,
                                                 const int* __restrict__ batch,
                                                 float* __restrict__ pooled, int N_) {
  int t = threadIdx.x;
  int lane = t & 63, w = t >> 6;
  int g16 = lane >> 4, l16 = lane & 15;
  int c0 = l16 * 8 + g16 * 2;                  // this lane's 2 output channels
  float2 bb = *(const float2*)&bL[c0];
  const uint4* hw4 = (const uint4*)hwb;
  int wid = blockIdx.x * 4 + w;
  int nw = gridDim.x * 4;
  float s1a = 0, s1b = 0, s2a = 0, s2b = 0;
  for (int n = wid; n < N_; n += nw) {
    int st = row_ptr[n], en = row_ptr[n + 1];
    float acc[8] = {0, 0, 0, 0, 0, 0, 0, 0};
    for (int chunk = st; chunk < en; chunk += 64) {
      int cnt = min(64, en - chunk);
      int idx = (lane < cnt) ? csr[chunk + lane] : N_;   // sentinel -> zero row
      int nit = (cnt + 3) >> 2;
      #pragma unroll 8
      for (int i = 0; i < nit; i++) {
        int s_ = __shfl(idx, i * 4 + g16);
        uint4 v = hw4[(size_t)s_ * 16 + l16];
        acc[0] += bflo(v.x); acc[1] += bfhi(v.x);
        acc[2] += bflo(v.y); acc[3] += bfhi(v.y);
        acc[4] += bflo(v.z); acc[5] += bfhi(v.z);
        acc[6] += bflo(v.w); acc[7] += bfhi(v.w);
      }
    }
    float dn = dis[n];
    // self row (premultiplied) added once, by group 0 only
    {
      uint4 v = hw4[(size_t)n * 16 + l16];
      float wc = (g16 == 0) ? 1.f : 0.f;
      acc[0] = fmaf(wc, bflo(v.x), acc[0]); acc[1] = fmaf(wc, bfhi(v.x), acc[1]);
      acc[2] = fmaf(wc, bflo(v.y), acc[2]); acc[3] = fmaf(wc, bfhi(v.y), acc[3]);
      acc[4] = fmaf(wc, bflo(v.z), acc[4]); acc[5] = fmaf(wc, bfhi(v.z), acc[5]);
      acc[6] = fmaf(wc, bflo(v.w), acc[6]); acc[7] = fmaf(wc, bfhi(v.w), acc[7]);
    }
    #pragma unroll
    for (int k = 0; k < 8; k++) {
      acc[k] += __shfl_xor(acc[k], 16);
      acc[k] += __shfl_xor(acc[k], 32);
    }
    float ta = (g16 & 1) ? acc[2] : acc[0];
    float tb = (g16 & 1) ? acc[6] : acc[4];
    float va = (g16 & 2) ? tb : ta;
    float tc = (g16 & 1) ? acc[3] : acc[1];
    float td = (g16 & 1) ? acc[7] : acc[5];
    float vb = (g16 & 2) ? td : tc;
    float ox = fmaxf(fmaf(va, dn, bb.x), 0.f);
    float oy = fmaxf(fmaf(vb, dn, bb.y), 0.f);
    s1a += ox; s1b += oy; s2a += ox * ox; s2b += oy * oy;
    if (FUSE_POOL) {
      int g = batch[n];
      atomicAdd(&pooled[g * 128 + c0], ox);
      atomicAdd(&pooled[g * 128 + c0 + 1], oy);
    } else {
      float2 o; o.x = ox; o.y = oy;
      *(float2*)&y[(size_t)n * 128 + c0] = o;
    }
  }
  __shared__ float rs[4][64][4];
  rs[w][lane][0] = s1a; rs[w][lane][1] = s1b;
  rs[w][lane][2] = s2a; rs[w][lane][3] = s2b;
  __syncthreads();
  int s = t >> 7, c = t & 127;
  int lsrc = (c >> 3) | (((c & 7) >> 1) << 4);
  int sl = (s << 1) | (c & 1);
  float a = rs[0][lsrc][sl] + rs[1][lsrc][sl] + rs[2][lsrc][sl] + rs[3][lsrc][sl];
  atomicAdd(s ? &S2[c] : &S1[c], a);
}

// fold BN3 into classifier
__global__ void k_prepC(const float* __restrict__ S1, const float* __restrict__ S2,
                        const float* __restrict__ g_, const float* __restrict__ b_,
                        const float* __restrict__ Wc1, const float* __restrict__ bc1,
                        float* __restrict__ Wc1p, float* __restrict__ bc1p, int N_) {
  __shared__ float sc[128], sh[128];
  int t = threadIdx.x;  // 128
  {
    float m = S1[t] / N_;
    float v = S2[t] / N_ - m * m;
    float s = g_[t] * rsqrtf(v + NEPS);
    sc[t] = s; sh[t] = b_[t] - m * s;
  }
  __syncthreads();
  for (int idx = t; idx < 128 * 64; idx += 128) Wc1p[idx] = sc[idx >> 6] * Wc1[idx];
  if (t < 64) {
    float acc = bc1[t];
    for (int k = 0; k < 128; k++) acc = fmaf(sh[k], Wc1[k * 64 + t], acc);
    bc1p[t] = acc;
  }
}

__device__ inline int lb_dev(const int* b, int n, int v) {
  int lo = 0, hi = n;
  while (lo < hi) { int mid = (lo + hi) >> 1; if (b[mid] < v) lo = mid + 1; else hi = mid; }
  return lo;
}

__global__ void k_cls(const float* __restrict__ pooled, const int* __restrict__ batch,
                      const float* __restrict__ Wc1p, const float* __restrict__ bc1p,
                      const float* __restrict__ Wc2, const float* __restrict__ bc2,
                      float* __restrict__ out, int N_, int G_) {
  __shared__ float p[128];
  __shared__ float z[64];
  __shared__ int s_lo, s_hi;
  int g = blockIdx.x, t = threadIdx.x;  // 64 threads
  if (t == 0) s_lo = lb_dev(batch, N_, g);
  if (t == 1) s_hi = lb_dev(batch, N_, g + 1);
  __syncthreads();
  float inv = 1.f / fmaxf((float)(s_hi - s_lo), 1.f);
  p[t] = pooled[g * 128 + t] * inv;
  p[t + 64] = pooled[g * 128 + 64 + t] * inv;
  __syncthreads();
  float acc = bc1p[t];
  for (int k = 0; k < 128; k++) acc = fmaf(p[k], Wc1p[k * 64 + t], acc);
  z[t] = fmaxf(acc, 0.f);
  __syncthreads();
  if (t < 2) {
    float o = bc2[t];
    for (int j = 0; j < 64; j++) o = fmaf(z[j], Wc2[j * 2 + t], o);
    out[g * 2 + t] = o;
  }
}

extern "C" void kernel_launch(void* const* d_in, const int* in_sizes, int n_in,
                              void* d_out, int out_size, void* d_ws, size_t ws_size,
                              hipStream_t stream) {
  const float* x    = (const float*)d_in[0];
  const int*   ei   = (const int*)d_in[1];
  const int*   batch= (const int*)d_in[2];
  const float* W1   = (const float*)d_in[3];
  const float* b1   = (const float*)d_in[4];
  const float* W2   = (const float*)d_in[5];
  const float* b2   = (const float*)d_in[6];
  const float* W3   = (const float*)d_in[7];
  const float* b3   = (const float*)d_in[8];
  const float* bn0g = (const float*)d_in[9];
  const float* bn0b = (const float*)d_in[10];
  const float* bn1g = (const float*)d_in[11];
  const float* bn1b = (const float*)d_in[12];
  const float* bn2g = (const float*)d_in[13];
  const float* bn2b = (const float*)d_in[14];
  const float* bn3g = (const float*)d_in[15];
  const float* bn3b = (const float*)d_in[16];
  const float* Wc1  = (const float*)d_in[17];
  const float* bc1  = (const float*)d_in[18];
  const float* Wc2  = (const float*)d_in[19];
  const float* bc2  = (const float*)d_in[20];

  const int N_ = in_sizes[2];
  const int E_ = in_sizes[1] / 2;
  const int G_ = out_size / 2;

  char* ws = (char*)d_ws;
  size_t off = 0;
  auto A = [&](size_t bytes) { size_t o = off; off = (off + bytes + 255) & ~(size_t)255; return o; };
  // zeroed region
  size_t o_deg   = A((size_t)N_ * 4);
  size_t o_stats = A(1024 * 4);
  size_t o_pool  = A((size_t)G_ * 128 * 4);
  size_t zero_end = off;
  size_t o_rowp  = A((size_t)(N_ + 1) * 4);
  size_t o_bsum  = A(256 * 4);
  size_t o_slot  = A((size_t)E_ * 4);
  size_t o_csr   = A((size_t)E_ * 4);
  size_t o_dis   = A((size_t)N_ * 4);
  size_t o_xp    = A((size_t)N_ * 16);
  size_t o_W1a   = A(384 * 4);
  size_t o_u1    = A(128 * 4);
  size_t o_Wp    = A(16384 * 4);
  size_t o_cb    = A(128 * 4);
  size_t o_Wc1p  = A(8192 * 4);
  size_t o_bc1p  = A(64 * 4);
  size_t o_bufB  = A((size_t)N_ * 128 * 4);          // f32 activations
  size_t o_bufAh = A(((size_t)N_ + 1) * 128 * 2);    // bf16 premultiplied hw (+sentinel row)
  (void)ws_size; (void)n_in;

  int*   deg_cnt = (int*)(ws + o_deg);
  float* stats   = (float*)(ws + o_stats);
  float* pooled  = (float*)(ws + o_pool);
  int*   row_ptr = (int*)(ws + o_rowp);
  int*   bsum    = (int*)(ws + o_bsum);
  int*   slot    = (int*)(ws + o_slot);
  int*   csr     = (int*)(ws + o_csr);
  float* dis     = (float*)(ws + o_dis);
  float4* xp     = (float4*)(ws + o_xp);
  float* W1a     = (float*)(ws + o_W1a);
  float* u1      = (float*)(ws + o_u1);
  float* Wp      = (float*)(ws + o_Wp);
  float* cb      = (float*)(ws + o_cb);
  float* Wc1p    = (float*)(ws + o_Wc1p);
  float* bc1p    = (float*)(ws + o_bc1p);
  float* bufB    = (float*)(ws + o_bufB);
  unsigned short* bufAh = (unsigned short*)(ws + o_bufAh);

  hipMemsetAsync(ws, 0, zero_end, stream);

  int nb_scan = (N_ + 255) / 256;

  k_degx<<<2048, 256, 0, stream>>>(ei, deg_cnt, slot, x, stats, N_, E_);
  k_scanA<<<nb_scan, 256, 0, stream>>>(deg_cnt, row_ptr + 1, bsum, N_);
  k_scanB<<<1, 256, 0, stream>>>(bsum, nb_scan);
  k_scanC<<<nb_scan, 256, 0, stream>>>(row_ptr, bsum, deg_cnt, x, dis, xp, N_);
  k_scatter<<<2048, 256, 0, stream>>>(ei, row_ptr, slot, csr, E_);
  k_prep0<<<1, 128, 0, stream>>>(stats, bn0g, bn0b, W1, W1a, u1, N_);

  // fused layer 1 (gather + 3->128 GEMM + relu + stats)
  k_layer1<<<2048, 256, 0, stream>>>(xp, csr, row_ptr, W1a, u1, b1, bufB,
                                     stats + 128, stats + 256, N_);

  // layer 2
  k_prepW<<<16, 256, 0, stream>>>(stats + 128, stats + 256, bn1g, bn1b, W2, Wp, cb, N_);
  k_gemm<<<(N_ + 63) / 64, 256, 0, stream>>>(bufB, Wp, cb, dis, bufAh, N_);
  k_gatherb<0><<<2048, 256, 0, stream>>>(bufAh, csr, row_ptr, dis, b2, bufB,
                                         stats + 384, stats + 512, batch, pooled, N_);

  // layer 3
  k_prepW<<<16, 256, 0, stream>>>(stats + 384, stats + 512, bn2g, bn2b, W3, Wp, cb, N_);
  k_gemm<<<(N_ + 63) / 64, 256, 0, stream>>>(bufB, Wp, cb, dis, bufAh, N_);
  k_gatherb<1><<<2048, 256, 0, stream>>>(bufAh, csr, row_ptr, dis, b3, nullptr,
                                         stats + 640, stats + 768, batch, pooled, N_);

  // classifier
  k_prepC<<<1, 128, 0, stream>>>(stats + 640, stats + 768, bn3g, bn3b, Wc1, bc1, Wc1p, bc1p, N_);
  k_cls<<<G_, 64, 0, stream>>>(pooled, batch, Wc1p, bc1p, Wc2, bc2, (float*)d_out, N_, G_);
}

// Round 5
// 358.068 us; speedup vs baseline: 2.9902x; 2.9902x over previous
//
#include <hip/hip_runtime.h>

#define NEPS 1e-5f

__device__ inline unsigned int bfpack(float a, float b) {
  unsigned int ua = __float_as_uint(a), ub = __float_as_uint(b);
  ua += 0x7fff + ((ua >> 16) & 1);
  ub += 0x7fff + ((ub >> 16) & 1);
  return (ua >> 16) | (ub & 0xffff0000u);
}
__device__ inline float bflo(unsigned int u) { return __uint_as_float(u << 16); }
__device__ inline float bfhi(unsigned int u) { return __uint_as_float(u & 0xffff0000u); }

// ---------------- CSR build ----------------
__global__ void k_deg(const int* __restrict__ ei, int* __restrict__ deg_cnt,
                      int* __restrict__ slot, int E_) {
  int i = blockIdx.x * blockDim.x + threadIdx.x;
  int stride = gridDim.x * blockDim.x;
  for (int e = i; e < E_; e += stride) slot[e] = atomicAdd(&deg_cnt[ei[E_ + e]], 1);
}

__global__ __launch_bounds__(256) void k_scanA(const int* __restrict__ cnt, int* __restrict__ rp1,
                                               int* __restrict__ bsum, int N_) {
  int b = blockIdx.x, t = threadIdx.x;
  int i = b * 256 + t;
  int lane = t & 63, w = t >> 6;
  int sv = (i < N_) ? cnt[i] : 0;
  #pragma unroll
  for (int off = 1; off < 64; off <<= 1) {
    int u = __shfl_up(sv, off);
    if (lane >= off) sv += u;
  }
  __shared__ int wsum[4];
  if (lane == 63) wsum[w] = sv;
  __syncthreads();
  int add = 0;
  for (int k = 0; k < w; k++) add += wsum[k];
  sv += add;
  if (i < N_) rp1[i] = sv;
  if (t == 255) bsum[b] = sv;
}

__global__ __launch_bounds__(256) void k_scanB(int* __restrict__ bsum, int NB) {
  int t = threadIdx.x;
  int lane = t & 63, w = t >> 6;
  int sv = (t < NB) ? bsum[t] : 0;
  #pragma unroll
  for (int off = 1; off < 64; off <<= 1) {
    int u = __shfl_up(sv, off);
    if (lane >= off) sv += u;
  }
  __shared__ int wsum[4];
  if (lane == 63) wsum[w] = sv;
  __syncthreads();
  int add = 0;
  for (int k = 0; k < w; k++) add += wsum[k];
  sv += add;
  if (t < NB) bsum[t] = sv;
}

// add block offsets; compute dis; pack xp = {x0,x1,x2,dis}; fused BN0 stats (1 atomic/stat/block)
__global__ __launch_bounds__(256) void k_scanC(int* __restrict__ row_ptr, const int* __restrict__ bsum,
                                               const int* __restrict__ deg_cnt, const float* __restrict__ x,
                                               float* __restrict__ dis, float4* __restrict__ xp,
                                               float* __restrict__ stats, int N_) {
  int b = blockIdx.x, t = threadIdx.x;
  int i = b * 256 + t;
  float s1[3] = {0, 0, 0}, s2[3] = {0, 0, 0};
  if (i == 0) row_ptr[0] = 0;
  if (i < N_) {
    int base = b ? bsum[b - 1] : 0;
    row_ptr[i + 1] += base;
    float dg = (float)deg_cnt[i] + 1.0f;
    float ds_ = rsqrtf(dg);
    dis[i] = ds_;
    float x0 = x[i * 3 + 0], x1 = x[i * 3 + 1], x2 = x[i * 3 + 2];
    float4 v; v.x = x0; v.y = x1; v.z = x2; v.w = ds_;
    xp[i] = v;
    s1[0] = x0; s1[1] = x1; s1[2] = x2;
    s2[0] = x0 * x0; s2[1] = x1 * x1; s2[2] = x2 * x2;
  }
  #pragma unroll
  for (int c = 0; c < 3; c++) {
    for (int off = 32; off > 0; off >>= 1) {
      s1[c] += __shfl_down(s1[c], off);
      s2[c] += __shfl_down(s2[c], off);
    }
  }
  __shared__ float rs[4][8];
  int lane = t & 63, w = t >> 6;
  if (lane == 0) {
    rs[w][0] = s1[0]; rs[w][1] = s1[1]; rs[w][2] = s1[2]; rs[w][3] = 0.f;
    rs[w][4] = s2[0]; rs[w][5] = s2[1]; rs[w][6] = s2[2]; rs[w][7] = 0.f;
  }
  __syncthreads();
  if (t < 8 && t != 3 && t != 7) {
    float a = rs[0][t] + rs[1][t] + rs[2][t] + rs[3][t];
    atomicAdd(&stats[t], a);
  }
}

// atomic-free scatter using precomputed slots
__global__ void k_scatter(const int* __restrict__ ei, const int* __restrict__ row_ptr,
                          const int* __restrict__ slot, int* __restrict__ csr, int E_) {
  int i = blockIdx.x * blockDim.x + threadIdx.x;
  int stride = gridDim.x * blockDim.x;
  for (int e = i; e < E_; e += stride) {
    csr[row_ptr[ei[E_ + e]] + slot[e]] = ei[e];
  }
}

// fold BN0 into W1
__global__ void k_prep0(const float* __restrict__ stats, const float* __restrict__ g0,
                        const float* __restrict__ b0, const float* __restrict__ W1,
                        float* __restrict__ W1a, float* __restrict__ u1, int N_) {
  __shared__ float a[3], dd[3];
  int t = threadIdx.x;
  if (t < 3) {
    float m = stats[t] / N_;
    float v = stats[4 + t] / N_ - m * m;
    float sc = g0[t] * rsqrtf(v + NEPS);
    a[t] = sc; dd[t] = b0[t] - m * sc;
  }
  __syncthreads();
  if (t < 128) {
    float u = 0.f;
    #pragma unroll
    for (int c = 0; c < 3; c++) {
      float w = W1[c * 128 + t];
      W1a[c * 128 + t] = a[c] * w;
      u = fmaf(dd[c], w, u);
    }
    u1[t] = u;
  }
}

// ---------------- fused layer 1: gather(x) + GEMM(3->128) + relu + stats ----------------
// Sp = 8 partial stat buffers, each 256 floats: [S1(128) | S2(128)]
__global__ __launch_bounds__(256) void k_layer1(const float4* __restrict__ xp,
                                                const int* __restrict__ csr,
                                                const int* __restrict__ row_ptr,
                                                const float* __restrict__ W1a,
                                                const float* __restrict__ u1,
                                                const float* __restrict__ b1,
                                                float* __restrict__ y,
                                                float* __restrict__ Sp,
                                                int N_) {
  __shared__ float wl[5 * 128];
  int t = threadIdx.x;
  for (int i = t; i < 384; i += 256) wl[i] = W1a[i];
  for (int i = t; i < 128; i += 256) { wl[384 + i] = u1[i]; wl[512 + i] = b1[i]; }
  __syncthreads();
  int lane = t & 63, w = t >> 6;
  int c0 = lane * 2;
  float2 w0 = *(const float2*)&wl[c0];
  float2 w1 = *(const float2*)&wl[128 + c0];
  float2 w2 = *(const float2*)&wl[256 + c0];
  float2 uu = *(const float2*)&wl[384 + c0];
  float2 bb = *(const float2*)&wl[512 + c0];
  int wid = blockIdx.x * 4 + w;
  int nw = gridDim.x * 4;
  float s1x = 0, s1y = 0, s2x = 0, s2y = 0;
  for (int n = wid; n < N_; n += nw) {
    int st = row_ptr[n], en = row_ptr[n + 1];
    float a0 = 0, a1 = 0, a2 = 0, sd = 0;
    for (int chunk = st; chunk < en; chunk += 64) {
      int cnt = min(64, en - chunk);
      if (lane < cnt) {
        float4 v = xp[csr[chunk + lane]];
        a0 = fmaf(v.w, v.x, a0);
        a1 = fmaf(v.w, v.y, a1);
        a2 = fmaf(v.w, v.z, a2);
        sd += v.w;
      }
    }
    #pragma unroll
    for (int m = 1; m < 64; m <<= 1) {
      a0 += __shfl_xor(a0, m);
      a1 += __shfl_xor(a1, m);
      a2 += __shfl_xor(a2, m);
      sd += __shfl_xor(sd, m);
    }
    float4 xn = xp[n];
    float dn = xn.w;
    a0 = fmaf(dn, xn.x, a0);
    a1 = fmaf(dn, xn.y, a1);
    a2 = fmaf(dn, xn.z, a2);
    sd += dn;
    float z0 = dn * a0, z1 = dn * a1, z2 = dn * a2, zw = dn * sd;
    float ox = fmaxf(fmaf(z0, w0.x, fmaf(z1, w1.x, fmaf(z2, w2.x, fmaf(zw, uu.x, bb.x)))), 0.f);
    float oy = fmaxf(fmaf(z0, w0.y, fmaf(z1, w1.y, fmaf(z2, w2.y, fmaf(zw, uu.y, bb.y)))), 0.f);
    s1x += ox; s1y += oy; s2x += ox * ox; s2y += oy * oy;
    float2 o; o.x = ox; o.y = oy;
    *(float2*)&y[(size_t)n * 128 + c0] = o;
  }
  __shared__ float rs[4][64][4];
  rs[w][lane][0] = s1x; rs[w][lane][1] = s1y;
  rs[w][lane][2] = s2x; rs[w][lane][3] = s2y;
  __syncthreads();
  int s = t >> 7, c = t & 127;
  int lsrc = c >> 1, sl = (s << 1) | (c & 1);
  float a = rs[0][lsrc][sl] + rs[1][lsrc][sl] + rs[2][lsrc][sl] + rs[3][lsrc][sl];
  float* base = Sp + (blockIdx.x & 7) * 256;
  atomicAdd(&base[s * 128 + c], a);
}

// fold BN(prev) into W  (16 blocks); sums 8 partial stat buffers
__global__ __launch_bounds__(256) void k_prepW(const float* __restrict__ Sp,
                                               const float* __restrict__ g_, const float* __restrict__ b_,
                                               const float* __restrict__ W, float* __restrict__ Wp,
                                               float* __restrict__ cb, int N_) {
  __shared__ float sc[128], sh[128];
  int t = threadIdx.x, b = blockIdx.x;
  if (t < 128) {
    float m_s = 0, v_s = 0;
    #pragma unroll
    for (int p = 0; p < 8; p++) { m_s += Sp[p * 256 + t]; v_s += Sp[p * 256 + 128 + t]; }
    float m = m_s / N_;
    float v = v_s / N_ - m * m;
    float s = g_[t] * rsqrtf(v + NEPS);
    sc[t] = s; sh[t] = b_[t] - m * s;
  }
  __syncthreads();
  for (int idx = b * 1024 + t; idx < (b + 1) * 1024; idx += 256) Wp[idx] = sc[idx >> 7] * W[idx];
  if (t < 8) {
    int j = b * 8 + t;
    float acc = 0;
    for (int k = 0; k < 128; k++) acc = fmaf(sh[k], W[k * 128 + j], acc);
    cb[j] = acc;
  }
}

// hwp = dis[n] * (y @ Wp + cb)  -> bf16 (premultiplied); row N_ zeroed (sentinel)
__global__ __launch_bounds__(256) void k_gemm(const float* __restrict__ y,
                                              const float* __restrict__ Wp,
                                              const float* __restrict__ cb,
                                              const float* __restrict__ dis,
                                              unsigned short* __restrict__ hwb, int N_) {
  int t = threadIdx.x;
  if (blockIdx.x == 0 && t < 64) ((unsigned int*)&hwb[(size_t)N_ * 128])[t] = 0;
  __shared__ float yl[64][128];
  int base = blockIdx.x * 64;
  for (int i = t; i < 64 * 32; i += 256) {
    int r = i >> 5;
    int cq = (i & 31) * 4;
    int n = base + r;
    float4 v = (n < N_) ? *(const float4*)&y[(size_t)n * 128 + cq] : float4{0, 0, 0, 0};
    *(float4*)&yl[r][cq] = v;
  }
  __syncthreads();
  int tn = t >> 5, tj = t & 31;
  float4 acc[8];
  float4 cbv = *(const float4*)&cb[tj * 4];
  #pragma unroll
  for (int r = 0; r < 8; r++) acc[r] = cbv;
  for (int kk = 0; kk < 128; kk++) {
    float4 wv = *(const float4*)&Wp[kk * 128 + tj * 4];
    #pragma unroll
    for (int r = 0; r < 8; r++) {
      float yv = yl[tn * 8 + r][kk];
      acc[r].x = fmaf(yv, wv.x, acc[r].x);
      acc[r].y = fmaf(yv, wv.y, acc[r].y);
      acc[r].z = fmaf(yv, wv.z, acc[r].z);
      acc[r].w = fmaf(yv, wv.w, acc[r].w);
    }
  }
  #pragma unroll
  for (int r = 0; r < 8; r++) {
    int n = base + tn * 8 + r;
    if (n < N_) {
      float dn = dis[n];
      uint2 o;
      o.x = bfpack(acc[r].x * dn, acc[r].y * dn);
      o.y = bfpack(acc[r].z * dn, acc[r].w * dn);
      *(uint2*)&hwb[(size_t)n * 128 + tj * 4] = o;
    }
  }
}

// gather of premultiplied bf16 rows; fused partial stats; optional fused pool
template <int FUSE_POOL>
__global__ __launch_bounds__(256) void k_gatherb(const unsigned short* __restrict__ hwb,
                                                 const int* __restrict__ csr,
                                                 const int* __restrict__ row_ptr,
                                                 const float* __restrict__ dis,
                                                 const float* __restrict__ bL,
                                                 float* __restrict__ y,
                                                 float* __restrict__ Sp,
                                                 const int* __restrict__ batch,
                                                 float* __restrict__ pooled, int N_) {
  int t = threadIdx.x;
  int lane = t & 63, w = t >> 6;
  int g16 = lane >> 4, l16 = lane & 15;
  int c0 = l16 * 8 + g16 * 2;                  // this lane's 2 output channels
  float2 bb = *(const float2*)&bL[c0];
  const uint4* hw4 = (const uint4*)hwb;
  int wid = blockIdx.x * 4 + w;
  int nw = gridDim.x * 4;
  float s1a = 0, s1b = 0, s2a = 0, s2b = 0;
  for (int n = wid; n < N_; n += nw) {
    int st = row_ptr[n], en = row_ptr[n + 1];
    float acc[8] = {0, 0, 0, 0, 0, 0, 0, 0};
    for (int chunk = st; chunk < en; chunk += 64) {
      int cnt = min(64, en - chunk);
      int idx = (lane < cnt) ? csr[chunk + lane] : N_;   // sentinel -> zero row
      int nit = (cnt + 3) >> 2;
      #pragma unroll 8
      for (int i = 0; i < nit; i++) {
        int s_ = __shfl(idx, i * 4 + g16);
        uint4 v = hw4[(size_t)s_ * 16 + l16];
        acc[0] += bflo(v.x); acc[1] += bfhi(v.x);
        acc[2] += bflo(v.y); acc[3] += bfhi(v.y);
        acc[4] += bflo(v.z); acc[5] += bfhi(v.z);
        acc[6] += bflo(v.w); acc[7] += bfhi(v.w);
      }
    }
    float dn = dis[n];
    {
      uint4 v = hw4[(size_t)n * 16 + l16];
      float wc = (g16 == 0) ? 1.f : 0.f;
      acc[0] = fmaf(wc, bflo(v.x), acc[0]); acc[1] = fmaf(wc, bfhi(v.x), acc[1]);
      acc[2] = fmaf(wc, bflo(v.y), acc[2]); acc[3] = fmaf(wc, bfhi(v.y), acc[3]);
      acc[4] = fmaf(wc, bflo(v.z), acc[4]); acc[5] = fmaf(wc, bfhi(v.z), acc[5]);
      acc[6] = fmaf(wc, bflo(v.w), acc[6]); acc[7] = fmaf(wc, bfhi(v.w), acc[7]);
    }
    #pragma unroll
    for (int k = 0; k < 8; k++) {
      acc[k] += __shfl_xor(acc[k], 16);
      acc[k] += __shfl_xor(acc[k], 32);
    }
    float ta = (g16 & 1) ? acc[2] : acc[0];
    float tb = (g16 & 1) ? acc[6] : acc[4];
    float va = (g16 & 2) ? tb : ta;
    float tc = (g16 & 1) ? acc[3] : acc[1];
    float td = (g16 & 1) ? acc[7] : acc[5];
    float vb = (g16 & 2) ? td : tc;
    float ox = fmaxf(fmaf(va, dn, bb.x), 0.f);
    float oy = fmaxf(fmaf(vb, dn, bb.y), 0.f);
    s1a += ox; s1b += oy; s2a += ox * ox; s2b += oy * oy;
    if (FUSE_POOL) {
      int g = batch[n];
      atomicAdd(&pooled[g * 128 + c0], ox);
      atomicAdd(&pooled[g * 128 + c0 + 1], oy);
    } else {
      float2 o; o.x = ox; o.y = oy;
      *(float2*)&y[(size_t)n * 128 + c0] = o;
    }
  }
  __shared__ float rs[4][64][4];
  rs[w][lane][0] = s1a; rs[w][lane][1] = s1b;
  rs[w][lane][2] = s2a; rs[w][lane][3] = s2b;
  __syncthreads();
  int s = t >> 7, c = t & 127;
  int lsrc = (c >> 3) | (((c & 7) >> 1) << 4);
  int sl = (s << 1) | (c & 1);
  float a = rs[0][lsrc][sl] + rs[1][lsrc][sl] + rs[2][lsrc][sl] + rs[3][lsrc][sl];
  float* base = Sp + (blockIdx.x & 7) * 256;
  atomicAdd(&base[s * 128 + c], a);
}

// fold BN3 into classifier; sums 8 partial stat buffers
__global__ void k_prepC(const float* __restrict__ Sp,
                        const float* __restrict__ g_, const float* __restrict__ b_,
                        const float* __restrict__ Wc1, const float* __restrict__ bc1,
                        float* __restrict__ Wc1p, float* __restrict__ bc1p, int N_) {
  __shared__ float sc[128], sh[128];
  int t = threadIdx.x;  // 128
  {
    float m_s = 0, v_s = 0;
    #pragma unroll
    for (int p = 0; p < 8; p++) { m_s += Sp[p * 256 + t]; v_s += Sp[p * 256 + 128 + t]; }
    float m = m_s / N_;
    float v = v_s / N_ - m * m;
    float s = g_[t] * rsqrtf(v + NEPS);
    sc[t] = s; sh[t] = b_[t] - m * s;
  }
  __syncthreads();
  for (int idx = t; idx < 128 * 64; idx += 128) Wc1p[idx] = sc[idx >> 6] * Wc1[idx];
  if (t < 64) {
    float acc = bc1[t];
    for (int k = 0; k < 128; k++) acc = fmaf(sh[k], Wc1[k * 64 + t], acc);
    bc1p[t] = acc;
  }
}

__device__ inline int lb_dev(const int* b, int n, int v) {
  int lo = 0, hi = n;
  while (lo < hi) { int mid = (lo + hi) >> 1; if (b[mid] < v) lo = mid + 1; else hi = mid; }
  return lo;
}

__global__ void k_cls(const float* __restrict__ pooled, const int* __restrict__ batch,
                      const float* __restrict__ Wc1p, const float* __restrict__ bc1p,
                      const float* __restrict__ Wc2, const float* __restrict__ bc2,
                      float* __restrict__ out, int N_, int G_) {
  __shared__ float p[128];
  __shared__ float z[64];
  __shared__ int s_lo, s_hi;
  int g = blockIdx.x, t = threadIdx.x;  // 64 threads
  if (t == 0) s_lo = lb_dev(batch, N_, g);
  if (t == 1) s_hi = lb_dev(batch, N_, g + 1);
  __syncthreads();
  float inv = 1.f / fmaxf((float)(s_hi - s_lo), 1.f);
  p[t] = pooled[g * 128 + t] * inv;
  p[t + 64] = pooled[g * 128 + 64 + t] * inv;
  __syncthreads();
  float acc = bc1p[t];
  for (int k = 0; k < 128; k++) acc = fmaf(p[k], Wc1p[k * 64 + t], acc);
  z[t] = fmaxf(acc, 0.f);
  __syncthreads();
  if (t < 2) {
    float o = bc2[t];
    for (int j = 0; j < 64; j++) o = fmaf(z[j], Wc2[j * 2 + t], o);
    out[g * 2 + t] = o;
  }
}

extern "C" void kernel_launch(void* const* d_in, const int* in_sizes, int n_in,
                              void* d_out, int out_size, void* d_ws, size_t ws_size,
                              hipStream_t stream) {
  const float* x    = (const float*)d_in[0];
  const int*   ei   = (const int*)d_in[1];
  const int*   batch= (const int*)d_in[2];
  const float* W1   = (const float*)d_in[3];
  const float* b1   = (const float*)d_in[4];
  const float* W2   = (const float*)d_in[5];
  const float* b2   = (const float*)d_in[6];
  const float* W3   = (const float*)d_in[7];
  const float* b3   = (const float*)d_in[8];
  const float* bn0g = (const float*)d_in[9];
  const float* bn0b = (const float*)d_in[10];
  const float* bn1g = (const float*)d_in[11];
  const float* bn1b = (const float*)d_in[12];
  const float* bn2g = (const float*)d_in[13];
  const float* bn2b = (const float*)d_in[14];
  const float* bn3g = (const float*)d_in[15];
  const float* bn3b = (const float*)d_in[16];
  const float* Wc1  = (const float*)d_in[17];
  const float* bc1  = (const float*)d_in[18];
  const float* Wc2  = (const float*)d_in[19];
  const float* bc2  = (const float*)d_in[20];

  const int N_ = in_sizes[2];
  const int E_ = in_sizes[1] / 2;
  const int G_ = out_size / 2;

  char* ws = (char*)d_ws;
  size_t off = 0;
  auto A = [&](size_t bytes) { size_t o = off; off = (off + bytes + 255) & ~(size_t)255; return o; };
  // zeroed region: deg, stats (BN0 8 floats @0; 3 layers x 8 partials x 256 floats), pooled
  size_t o_deg   = A((size_t)N_ * 4);
  size_t o_stats = A((size_t)(256 + 3 * 2048) * 4);
  size_t o_pool  = A((size_t)G_ * 128 * 4);
  size_t zero_end = off;
  size_t o_rowp  = A((size_t)(N_ + 1) * 4);
  size_t o_bsum  = A(256 * 4);
  size_t o_slot  = A((size_t)E_ * 4);
  size_t o_csr   = A((size_t)E_ * 4);
  size_t o_dis   = A((size_t)N_ * 4);
  size_t o_xp    = A((size_t)N_ * 16);
  size_t o_W1a   = A(384 * 4);
  size_t o_u1    = A(128 * 4);
  size_t o_Wp    = A(16384 * 4);
  size_t o_cb    = A(128 * 4);
  size_t o_Wc1p  = A(8192 * 4);
  size_t o_bc1p  = A(64 * 4);
  size_t o_bufB  = A((size_t)N_ * 128 * 4);          // f32 activations
  size_t o_bufAh = A(((size_t)N_ + 1) * 128 * 2);    // bf16 premultiplied hw (+sentinel row)
  (void)ws_size; (void)n_in;

  int*   deg_cnt = (int*)(ws + o_deg);
  float* stats   = (float*)(ws + o_stats);
  float* Sp1     = stats + 256;
  float* Sp2     = stats + 256 + 2048;
  float* Sp3     = stats + 256 + 4096;
  float* pooled  = (float*)(ws + o_pool);
  int*   row_ptr = (int*)(ws + o_rowp);
  int*   bsum    = (int*)(ws + o_bsum);
  int*   slot    = (int*)(ws + o_slot);
  int*   csr     = (int*)(ws + o_csr);
  float* dis     = (float*)(ws + o_dis);
  float4* xp     = (float4*)(ws + o_xp);
  float* W1a     = (float*)(ws + o_W1a);
  float* u1      = (float*)(ws + o_u1);
  float* Wp      = (float*)(ws + o_Wp);
  float* cb      = (float*)(ws + o_cb);
  float* Wc1p    = (float*)(ws + o_Wc1p);
  float* bc1p    = (float*)(ws + o_bc1p);
  float* bufB    = (float*)(ws + o_bufB);
  unsigned short* bufAh = (unsigned short*)(ws + o_bufAh);

  hipMemsetAsync(ws, 0, zero_end, stream);

  int nb_scan = (N_ + 255) / 256;

  k_deg<<<2048, 256, 0, stream>>>(ei, deg_cnt, slot, E_);
  k_scanA<<<nb_scan, 256, 0, stream>>>(deg_cnt, row_ptr + 1, bsum, N_);
  k_scanB<<<1, 256, 0, stream>>>(bsum, nb_scan);
  k_scanC<<<nb_scan, 256, 0, stream>>>(row_ptr, bsum, deg_cnt, x, dis, xp, stats, N_);
  k_scatter<<<2048, 256, 0, stream>>>(ei, row_ptr, slot, csr, E_);
  k_prep0<<<1, 128, 0, stream>>>(stats, bn0g, bn0b, W1, W1a, u1, N_);

  // fused layer 1 (gather + 3->128 GEMM + relu + partial stats)
  k_layer1<<<2048, 256, 0, stream>>>(xp, csr, row_ptr, W1a, u1, b1, bufB, Sp1, N_);

  // layer 2
  k_prepW<<<16, 256, 0, stream>>>(Sp1, bn1g, bn1b, W2, Wp, cb, N_);
  k_gemm<<<(N_ + 63) / 64, 256, 0, stream>>>(bufB, Wp, cb, dis, bufAh, N_);
  k_gatherb<0><<<2048, 256, 0, stream>>>(bufAh, csr, row_ptr, dis, b2, bufB, Sp2,
                                         batch, pooled, N_);

  // layer 3
  k_prepW<<<16, 256, 0, stream>>>(Sp2, bn2g, bn2b, W3, Wp, cb, N_);
  k_gemm<<<(N_ + 63) / 64, 256, 0, stream>>>(bufB, Wp, cb, dis, bufAh, N_);
  k_gatherb<1><<<2048, 256, 0, stream>>>(bufAh, csr, row_ptr, dis, b3, nullptr, Sp3,
                                         batch, pooled, N_);

  // classifier
  k_prepC<<<1, 128, 0, stream>>>(Sp3, bn3g, bn3b, Wc1, bc1, Wc1p, bc1p, N_);
  k_cls<<<G_, 64, 0, stream>>>(pooled, batch, Wc1p, bc1p, Wc2, bc2, (float*)d_out, N_, G_);
}